// Round 5
// baseline (153.199 us; speedup 1.0000x reference)
//
#include <hip/hip_runtime.h>
#include <stdint.h>

#define BATCH 256
#define IDIM  8192
#define ODIM  8192
#define MS    64
#define IC    128
#define OC    128
#define NB    1024

#define KSPLIT 4
#define NIB (IC / KSPLIT)      // 32 ib-iterations per workgroup

typedef __bf16 bf16x8 __attribute__((ext_vector_type(8)));
typedef float  floatx4 __attribute__((ext_vector_type(4)));

__device__ __forceinline__ unsigned short f32_to_bf16(float f) {
    unsigned int u = __float_as_uint(f);
    u += 0x7FFFu + ((u >> 16) & 1u);
    return (unsigned short)(u >> 16);
}

// ======================= kernel 1: layout conversion =======================
// A-frag layout: frag(g,ib,kk) at ushort offset ((g*128+ib)*2+kk)*512 + lane*8
//   lane L holds x[g*16 + (L&15)][ib*64 + kk*32 + (L>>4)*8 + j]  (A[m][k], m=L&15, k=quad*8+j)
// B-frag layout: frag(p,ng,kk) at ushort offset ((p*4+ng)*2+kk)*512 + lane*8
//   lane L holds blocks[p][kk*32 + (L>>4)*8 + j][ng*16 + (L&15)]  (B[n][k] = W^T)
// parts transposed: pT[ob*128 + ib] = parts[ib*128 + ob]
#define XCONV_BLKS 1024
#define PT_BLKS 64
__global__ void k_convert(const float* __restrict__ x, const float* __restrict__ blocks,
                          const int* __restrict__ parts,
                          unsigned short* __restrict__ xa, unsigned short* __restrict__ bbuf,
                          int* __restrict__ pT) {
    __shared__ float tile[MS][MS + 1];
    int b = blockIdx.x;
    if (b < NB) {
        const float4* src4 = (const float4*)(blocks + (size_t)b * MS * MS);
        #pragma unroll
        for (int i = 0; i < 4; ++i) {
            int slot = i * 256 + threadIdx.x;
            int r = slot >> 4, c4 = (slot & 15) * 4;
            float4 v = src4[slot];
            tile[r][c4 + 0] = v.x; tile[r][c4 + 1] = v.y;
            tile[r][c4 + 2] = v.z; tile[r][c4 + 3] = v.w;
        }
        __syncthreads();
        unsigned short* dst = bbuf + (size_t)b * 4096;
        #pragma unroll
        for (int i = 0; i < 2; ++i) {
            int oo = i * 256 + threadIdx.x;           // 512 fragment-slots per block
            int L = oo & 63, kk = (oo >> 6) & 1, ng = (oo >> 7) & 3;
            int row = L & 15, quad = L >> 4;
            union { unsigned short s[8]; uint4 v; } u;
            #pragma unroll
            for (int j = 0; j < 8; ++j)
                u.s[j] = f32_to_bf16(tile[kk * 32 + quad * 8 + j][ng * 16 + row]);
            *(uint4*)(dst + oo * 8) = u.v;            // coalesced 16B stores
        }
    } else if (b < NB + XCONV_BLKS) {
        int o = (b - NB) * 256 + threadIdx.x;         // 262144 fragment-slots
        int L = o & 63, kk = (o >> 6) & 1, ib = (o >> 7) & 127, g = o >> 14;
        int m  = g * 16 + (L & 15);
        int k0 = ib * 64 + kk * 32 + (L >> 4) * 8;
        const float* src = x + (size_t)m * IDIM + k0;
        float4 a = *(const float4*)src, c = *(const float4*)(src + 4);
        union { unsigned short s[8]; uint4 v; } u;
        u.s[0] = f32_to_bf16(a.x); u.s[1] = f32_to_bf16(a.y);
        u.s[2] = f32_to_bf16(a.z); u.s[3] = f32_to_bf16(a.w);
        u.s[4] = f32_to_bf16(c.x); u.s[5] = f32_to_bf16(c.y);
        u.s[6] = f32_to_bf16(c.z); u.s[7] = f32_to_bf16(c.w);
        *(uint4*)(xa + (size_t)o * 8) = u.v;
    } else {
        int t = (b - NB - XCONV_BLKS) * 256 + threadIdx.x;   // 16384
        int oc = t >> 7, ic = t & 127;
        pT[t] = parts[ic * OC + oc];
    }
}

// ======================= kernel 2: no-LDS register-pipelined GEMM =======================
// 4 waves/wg, wave w = m-tile (rows w*64..+63), wg covers n = ob*64..+63, K-slice ks.
// No __shared__, no barriers: fragments loaded coalesced direct to VGPRs,
// software-pipelined one ib ahead -> compiler free to use fine-grained vmcnt(N).
__global__ __launch_bounds__(256, 2)
void k_mosaic_gemm(const unsigned short* __restrict__ xa,
                   const unsigned short* __restrict__ bbuf,
                   const int* __restrict__ pT,
                   float* __restrict__ partial) {
    const int tid  = threadIdx.x;
    const int lane = tid & 63;
    const int w    = tid >> 6;
    const int ob   = blockIdx.x;     // 0..127
    const int ks   = blockIdx.y;     // 0..KSPLIT-1
    const int ib0  = ks * NIB;

    const int row  = lane & 15;
    const int quad = lane >> 4;

    // A base pointers per (mi,kk); ib stride = 1024 ushorts
    const unsigned short* abase[4][2];
    #pragma unroll
    for (int mi = 0; mi < 4; ++mi)
        #pragma unroll
        for (int kk = 0; kk < 2; ++kk)
            abase[mi][kk] = xa + (size_t)(w * 4 + mi) * 131072 + kk * 512 + lane * 8;

    const int* pp = pT + ob * 128 + ib0;

    bf16x8 ac[4][2], bc[4][2], an[4][2], bn[4][2];

    floatx4 acc[4][4];
    #pragma unroll
    for (int mi = 0; mi < 4; ++mi)
        #pragma unroll
        for (int ni = 0; ni < 4; ++ni)
            acc[mi][ni] = (floatx4){0.f, 0.f, 0.f, 0.f};

#define LOAD_A(dst, ib_) do { \
    _Pragma("unroll") for (int mi = 0; mi < 4; ++mi) \
    _Pragma("unroll") for (int kk = 0; kk < 2; ++kk) \
        dst[mi][kk] = *(const bf16x8*)(abase[mi][kk] + (size_t)(ib0 + (ib_)) * 1024); } while (0)
#define LOAD_B(dst, p_) do { \
    const unsigned short* bp = bbuf + (size_t)(p_) * 4096 + lane * 8; \
    _Pragma("unroll") for (int ng = 0; ng < 4; ++ng) \
    _Pragma("unroll") for (int kk = 0; kk < 2; ++kk) \
        dst[ng][kk] = *(const bf16x8*)(bp + (ng * 2 + kk) * 512); } while (0)
#define DO_MFMA(a_, b_) do { \
    _Pragma("unroll") for (int kk = 0; kk < 2; ++kk) \
    _Pragma("unroll") for (int mi = 0; mi < 4; ++mi) \
    _Pragma("unroll") for (int ni = 0; ni < 4; ++ni) \
        acc[mi][ni] = __builtin_amdgcn_mfma_f32_16x16x32_bf16(a_[mi][kk], b_[ni][kk], acc[mi][ni], 0, 0, 0); } while (0)

    // prologue
    LOAD_A(ac, 0);
    LOAD_B(bc, pp[0]);

    for (int ii = 0; ii < NIB; ii += 2) {
        int i1 = (ii + 1 < NIB) ? ii + 1 : NIB - 1;
        int i2 = (ii + 2 < NIB) ? ii + 2 : NIB - 1;
        LOAD_A(an, i1);
        LOAD_B(bn, pp[i1]);
        DO_MFMA(ac, bc);
        LOAD_A(ac, i2);
        LOAD_B(bc, pp[i2]);
        DO_MFMA(an, bn);
    }

    // epilogue: C/D layout col = lane&15, row = quad*4 + reg (R2/R4-verified)
    float* out = partial + (size_t)ks * BATCH * ODIM;
    #pragma unroll
    for (int mi = 0; mi < 4; ++mi)
        #pragma unroll
        for (int ni = 0; ni < 4; ++ni)
            #pragma unroll
            for (int r = 0; r < 4; ++r) {
                int rowg = w * 64 + mi * 16 + quad * 4 + r;
                int colg = ob * 64 + ni * 16 + row;
                out[(size_t)rowg * ODIM + colg] = acc[mi][ni][r];
            }
}

// ======================= kernel 3: sum KSPLIT partials + bias =======================
__global__ void k_reduce_bias(const float* __restrict__ partial,
                              const float* __restrict__ bias,
                              float* __restrict__ out) {
    int t = blockIdx.x * 256 + threadIdx.x;
    const float4* b4 = (const float4*)bias;
    float4 c = b4[t & (ODIM / 4 - 1)];
    float4 r = {c.x, c.y, c.z, c.w};
    #pragma unroll
    for (int k = 0; k < KSPLIT; ++k) {
        const float4* p = (const float4*)(partial + (size_t)k * BATCH * ODIM);
        float4 a = p[t];
        r.x += a.x; r.y += a.y; r.z += a.z; r.w += a.w;
    }
    ((float4*)out)[t] = r;
}

extern "C" void kernel_launch(void* const* d_in, const int* in_sizes, int n_in,
                              void* d_out, int out_size, void* d_ws, size_t ws_size,
                              hipStream_t stream) {
    const float* x      = (const float*)d_in[0];
    const float* blocks = (const float*)d_in[1];
    const float* bias   = (const float*)d_in[2];
    const int*   parts  = (const int*)d_in[3];
    float* out = (float*)d_out;

    char* ws = (char*)d_ws;
    unsigned short* xa      = (unsigned short*)ws;                      // 4 MB  A-frags
    unsigned short* bbuf    = (unsigned short*)(ws + (4u << 20));       // 8 MB  B-frags
    int*            pTr     = (int*)(ws + (12u << 20));                 // 64 KB parts^T
    float*          partial = (float*)(ws + (13u << 20));               // 32 MB (4 x 8 MB)

    k_convert<<<NB + XCONV_BLKS + PT_BLKS, 256, 0, stream>>>(x, blocks, parts, xa, bbuf, pTr);
    k_mosaic_gemm<<<dim3(OC, KSPLIT), 256, 0, stream>>>(xa, bbuf, pTr, partial);
    k_reduce_bias<<<(BATCH * ODIM) / (256 * 4), 256, 0, stream>>>(partial, bias, out);
}

// Round 6
// 120.617 us; speedup vs baseline: 1.2701x; 1.2701x over previous
//
#include <hip/hip_runtime.h>
#include <stdint.h>

#define BATCH 256
#define IDIM  8192
#define ODIM  8192
#define MS    64
#define IC    128
#define OC    128
#define NB    1024

#define TM 128
#define TN 128
#define KSPLIT 4
#define NIB (IC / KSPLIT)      // 32 ib-iterations per workgroup

typedef __bf16 bf16x8 __attribute__((ext_vector_type(8)));
typedef float  floatx4 __attribute__((ext_vector_type(4)));

// s_waitcnt imm: vmcnt[3:0]|[15:14], expcnt [6:4]=0x7 (dont-care), lgkmcnt [11:8]=0xF (dont-care)
#define WAITCNT_VM(n) ((((n) & 15) | (((n) >> 4) << 14)) | 0x70 | 0xF00)

__device__ __forceinline__ void async_load16(unsigned short* lds_p, const unsigned short* g_p) {
    __builtin_amdgcn_global_load_lds(
        (const __attribute__((address_space(1))) unsigned int*)g_p,
        (__attribute__((address_space(3))) unsigned int*)lds_p,
        16, 0, 0);
}

__device__ __forceinline__ unsigned short f32_to_bf16(float f) {
    unsigned int u = __float_as_uint(f);
    u += 0x7FFFu + ((u >> 16) & 1u);
    return (unsigned short)(u >> 16);
}

// ---- kernel 1: blocks -> bf16 [b][c][r] | x -> bf16 row-major | parts -> pT ----
#define XCONV_BLKS 1024
#define PT_BLKS 64
__global__ void k_convert(const float* __restrict__ x, const float* __restrict__ blocks,
                          const int* __restrict__ parts,
                          unsigned short* __restrict__ xb, unsigned short* __restrict__ bt,
                          int* __restrict__ pT) {
    __shared__ float tile[MS][MS + 1];
    int b = blockIdx.x;
    if (b < NB) {
        const float4* src4 = (const float4*)(blocks + (size_t)b * MS * MS);
        unsigned short* dst = bt + (size_t)b * MS * MS;
        #pragma unroll
        for (int i = 0; i < 4; ++i) {
            int slot = i * 256 + threadIdx.x;
            int r = slot >> 4, c4 = (slot & 15) * 4;
            float4 v = src4[slot];
            tile[r][c4 + 0] = v.x; tile[r][c4 + 1] = v.y;
            tile[r][c4 + 2] = v.z; tile[r][c4 + 3] = v.w;
        }
        __syncthreads();
        #pragma unroll
        for (int i = 0; i < 2; ++i) {
            int slot = i * 256 + threadIdx.x;
            int c = slot >> 3, o = slot & 7;
            union { unsigned short s[8]; uint4 v; } u;
            #pragma unroll
            for (int j = 0; j < 8; ++j) u.s[j] = f32_to_bf16(tile[o * 8 + j][c]);
            *(uint4*)(dst + c * MS + o * 8) = u.v;
        }
    } else if (b < NB + XCONV_BLKS) {
        int t = (b - NB) * 256 + threadIdx.x;
        const float4* x4 = (const float4*)x;
        float4 a = x4[2 * t], bb = x4[2 * t + 1];
        union { unsigned short s[8]; uint4 v; } u;
        u.s[0] = f32_to_bf16(a.x);  u.s[1] = f32_to_bf16(a.y);
        u.s[2] = f32_to_bf16(a.z);  u.s[3] = f32_to_bf16(a.w);
        u.s[4] = f32_to_bf16(bb.x); u.s[5] = f32_to_bf16(bb.y);
        u.s[6] = f32_to_bf16(bb.z); u.s[7] = f32_to_bf16(bb.w);
        ((uint4*)xb)[t] = u.v;
    } else {
        int t = (b - NB - XCONV_BLKS) * 256 + threadIdx.x;   // 16384
        int oc = t >> 7, ic = t & 127;
        pT[t] = parts[ic * OC + oc];                          // pT[ob][ib]
    }
}

// ---- kernel 2: GEMM, 128x128 tile, double-buffered LDS, raw barrier + vmcnt(8) ----
// LDS XOR swizzle (verified 0 conflicts): LDS[r][oct] = global[r][oct ^ (r&7)]
__global__ __launch_bounds__(256, 2)
void k_mosaic_gemm(const unsigned short* __restrict__ xb,
                   const unsigned short* __restrict__ bt,
                   const int* __restrict__ pT,
                   float* __restrict__ partial) {
    __shared__ __align__(16) unsigned short a_lds[2][TM * MS];   // 2 x 16 KB
    __shared__ __align__(16) unsigned short b_lds[2][TN * MS];   // 2 x 16 KB

    const int tid  = threadIdx.x;
    const int lane = tid & 63;
    const int wave = tid >> 6;
    const int wrow = wave >> 1;
    const int wcol = wave & 1;
    const int nt = blockIdx.x;       // 0..63
    const int mt = blockIdx.y;       // 0..1
    const int ks = blockIdx.z;       // 0..3

    const int m0  = mt * TM;
    const int ob0 = nt * 2;
    const int ib0 = ks * NIB;

    const int row  = lane & 15;
    const int quad = lane >> 4;

    // preload all 32 iterations' part indices into lane registers (one vmem pair, pre-loop)
    int pv0 = 0, pv1 = 0;
    {
        int li = lane & 31;
        pv0 = pT[ob0 * IC + ib0 + li];
        pv1 = pT[(ob0 + 1) * IC + ib0 + li];
    }

    // iteration-invariant ds_read element offsets
    int a_off[2][4], b_off[2][4];
    #pragma unroll
    for (int kk = 0; kk < 2; ++kk) {
        int oct = kk * 4 + quad;
        #pragma unroll
        for (int mi = 0; mi < 4; ++mi) {
            int r = wrow * 64 + mi * 16 + row;
            a_off[kk][mi] = r * MS + ((oct ^ (r & 7)) << 3);
        }
        #pragma unroll
        for (int ni = 0; ni < 4; ++ni) {
            int n = wcol * 64 + ni * 16 + row;
            b_off[kk][ni] = n * MS + ((oct ^ (n & 7)) << 3);
        }
    }

    floatx4 acc[4][4];
    #pragma unroll
    for (int mi = 0; mi < 4; ++mi)
        #pragma unroll
        for (int ni = 0; ni < 4; ++ni)
            acc[mi][ni] = (floatx4){0.f, 0.f, 0.f, 0.f};

    // 8 global_load_lds per thread per STAGE (4 A + 4 B) — vmcnt counting relies on this
#define STAGE(buf, ib_, p0_, p1_) do {                                        \
    _Pragma("unroll")                                                         \
    for (int j = 0; j < 4; ++j) {                                             \
        int slot = j * 256 + tid;                                             \
        int m = slot >> 3;                                                    \
        int oct = (slot & 7) ^ (m & 7);                                       \
        async_load16(&a_lds[buf][slot * 8],                                   \
                     xb + (size_t)(m0 + m) * IDIM + (ib_) * MS + oct * 8);    \
    }                                                                         \
    _Pragma("unroll")                                                         \
    for (int j = 0; j < 4; ++j) {                                             \
        int slot = j * 256 + tid;                                             \
        int n = slot >> 3;                                                    \
        int oct = (slot & 7) ^ (n & 7);                                       \
        int p = (j < 2) ? (p0_) : (p1_);                                      \
        async_load16(&b_lds[buf][slot * 8],                                   \
                     bt + (size_t)p * (MS * MS) + (n & 63) * MS + oct * 8);   \
    } } while (0)

#define COMPUTE(buf) do {                                                     \
    _Pragma("unroll")                                                         \
    for (int kk = 0; kk < 2; ++kk) {                                          \
        bf16x8 af[4], bfr[4];                                                 \
        _Pragma("unroll")                                                     \
        for (int mi = 0; mi < 4; ++mi)                                        \
            af[mi] = *(const bf16x8*)&a_lds[buf][a_off[kk][mi]];              \
        _Pragma("unroll")                                                     \
        for (int ni = 0; ni < 4; ++ni)                                        \
            bfr[ni] = *(const bf16x8*)&b_lds[buf][b_off[kk][ni]];             \
        _Pragma("unroll")                                                     \
        for (int mi = 0; mi < 4; ++mi)                                        \
            _Pragma("unroll")                                                 \
            for (int ni = 0; ni < 4; ++ni)                                    \
                acc[mi][ni] = __builtin_amdgcn_mfma_f32_16x16x32_bf16(        \
                    af[mi], bfr[ni], acc[mi][ni], 0, 0, 0);                   \
    } } while (0)

    // prologue: stage iter 0 into buf 0
    {
        int p0 = __shfl(pv0, 0), p1 = __shfl(pv1, 0);
        STAGE(0, ib0 + 0, p0, p1);
    }

    for (int i = 0; i < NIB - 1; ++i) {
        int p0n = __shfl(pv0, i + 1), p1n = __shfl(pv1, i + 1);
        STAGE((i + 1) & 1, ib0 + i + 1, p0n, p1n);        // prefetch next (8 loads in flight)
        __builtin_amdgcn_s_waitcnt(WAITCNT_VM(8));        // drain iter i's loads only
        __builtin_amdgcn_s_barrier();                      // iter i data visible to all waves
        COMPUTE(i & 1);
        __builtin_amdgcn_s_barrier();                      // all done reading buf before overwrite
    }
    // final iteration
    __builtin_amdgcn_s_waitcnt(WAITCNT_VM(0));
    __builtin_amdgcn_s_barrier();
    COMPUTE((NIB - 1) & 1);

    // epilogue: C/D layout col = lane&15, row = quad*4 + reg
    float* out = partial + (size_t)ks * BATCH * ODIM;
    #pragma unroll
    for (int mi = 0; mi < 4; ++mi)
        #pragma unroll
        for (int ni = 0; ni < 4; ++ni)
            #pragma unroll
            for (int r = 0; r < 4; ++r) {
                int rowg = m0 + wrow * 64 + mi * 16 + quad * 4 + r;
                int colg = nt * TN + wcol * 64 + ni * 16 + row;
                out[(size_t)rowg * ODIM + colg] = acc[mi][ni][r];
            }
}

// ---- kernel 3: sum KSPLIT partials + bias ----
__global__ void k_reduce_bias(const float* __restrict__ partial,
                              const float* __restrict__ bias,
                              float* __restrict__ out) {
    int t = blockIdx.x * 256 + threadIdx.x;
    const float4* b4 = (const float4*)bias;
    float4 c = b4[t & (ODIM / 4 - 1)];
    float4 r = {c.x, c.y, c.z, c.w};
    #pragma unroll
    for (int k = 0; k < KSPLIT; ++k) {
        const float4* p = (const float4*)(partial + (size_t)k * BATCH * ODIM);
        float4 a = p[t];
        r.x += a.x; r.y += a.y; r.z += a.z; r.w += a.w;
    }
    ((float4*)out)[t] = r;
}

extern "C" void kernel_launch(void* const* d_in, const int* in_sizes, int n_in,
                              void* d_out, int out_size, void* d_ws, size_t ws_size,
                              hipStream_t stream) {
    const float* x      = (const float*)d_in[0];
    const float* blocks = (const float*)d_in[1];
    const float* bias   = (const float*)d_in[2];
    const int*   parts  = (const int*)d_in[3];
    float* out = (float*)d_out;

    char* ws = (char*)d_ws;
    unsigned short* xb      = (unsigned short*)ws;                      // 4 MB
    unsigned short* btb     = (unsigned short*)(ws + (4u << 20));       // 8 MB
    int*            pTr     = (int*)(ws + (12u << 20));                 // 64 KB
    float*          partial = (float*)(ws + (13u << 20));               // 32 MB

    k_convert<<<NB + XCONV_BLKS + PT_BLKS, 256, 0, stream>>>(x, blocks, parts, xb, btb, pTr);
    k_mosaic_gemm<<<dim3(ODIM / TN, BATCH / TM, KSPLIT), 256, 0, stream>>>(xb, btb, pTr, partial);
    k_reduce_bias<<<(BATCH * ODIM) / (256 * 4), 256, 0, stream>>>(partial, bias, out);
}